// Round 1
// baseline (1465.664 us; speedup 1.0000x reference)
//
#include <hip/hip_runtime.h>
#include <hip/hip_bf16.h>
#include <math.h>

#define N_NODES 50000
#define N_EDGES 500000
#define H 128
#define NL 3
#define SCAN_B 256
#define NCHUNK ((N_NODES + SCAN_B - 1) / SCAN_B)

typedef short short8v __attribute__((ext_vector_type(8)));
typedef float f32x4 __attribute__((ext_vector_type(4)));
typedef unsigned short ushort8v __attribute__((ext_vector_type(8)));
typedef unsigned short ushort4v __attribute__((ext_vector_type(4)));

__device__ __forceinline__ unsigned short f2b(float f) {
  __hip_bfloat16 h = __float2bfloat16(f);
  return __builtin_bit_cast(unsigned short, h);
}
__device__ __forceinline__ float b2f(unsigned short s) {
  unsigned u = (unsigned)s << 16;
  return __builtin_bit_cast(float, u);
}

// ---------------- counting sort of edges by dst ----------------

__global__ void k_deg_i(const int* __restrict__ dst, int* __restrict__ degC) {
  int e = blockIdx.x * blockDim.x + threadIdx.x;
  if (e < N_EDGES) atomicAdd(&degC[dst[e]], 1);
}

__global__ void k_inv(const int* __restrict__ degC, float* __restrict__ invd) {
  int i = blockIdx.x * blockDim.x + threadIdx.x;
  if (i < N_NODES) invd[i] = 1.0f / fmaxf((float)degC[i], 1.0f);
}

__global__ void k_scan1(const int* __restrict__ degC, int* __restrict__ cursor,
                        int* __restrict__ chunkSum) {
  __shared__ int s[SCAN_B];
  int t = threadIdx.x, i = blockIdx.x * SCAN_B + t;
  int v = (i < N_NODES) ? degC[i] : 0;
  s[t] = v;
  __syncthreads();
  for (int o = 1; o < SCAN_B; o <<= 1) {
    int u = (t >= o) ? s[t - o] : 0;
    __syncthreads();
    s[t] += u;
    __syncthreads();
  }
  if (i < N_NODES) cursor[i] = s[t] - v;
  if (t == SCAN_B - 1) chunkSum[blockIdx.x] = s[t];
}

__global__ void k_scan2(int* __restrict__ chunkSum) {
  __shared__ int s[SCAN_B];
  int t = threadIdx.x;
  int v = (t < NCHUNK) ? chunkSum[t] : 0;
  s[t] = v;
  __syncthreads();
  for (int o = 1; o < SCAN_B; o <<= 1) {
    int u = (t >= o) ? s[t - o] : 0;
    __syncthreads();
    s[t] += u;
    __syncthreads();
  }
  if (t < NCHUNK) chunkSum[t] = s[t] - v;
}

__global__ void k_scan3(int* __restrict__ cursor, const int* __restrict__ chunkSum) {
  int i = blockIdx.x * SCAN_B + threadIdx.x;
  if (i < N_NODES) cursor[i] += chunkSum[blockIdx.x];
}

__global__ void k_scatter_sort(const int* __restrict__ dst, int* __restrict__ cursor,
                               int* __restrict__ sorted) {
  int e = blockIdx.x * blockDim.x + threadIdx.x;
  if (e < N_EDGES) {
    int p = atomicAdd(&cursor[dst[e]], 1);
    sorted[p] = e;
  }
}

// ---------------- fp32 -> bf16 conversions ----------------

__global__ void k_cvt_x(const float* __restrict__ x, unsigned short* __restrict__ xb, int n4) {
  int i = blockIdx.x * blockDim.x + threadIdx.x;
  if (i < n4) {
    float4 v = ((const float4*)x)[i];
    ushort4v o;
    o[0] = f2b(v.x); o[1] = f2b(v.y); o[2] = f2b(v.z); o[3] = f2b(v.w);
    ((ushort4v*)xb)[i] = o;
  }
}

// src [L][K][N] fp32 -> dst [L][N][K] bf16
__global__ void k_cvt_wt(const float* __restrict__ src, unsigned short* __restrict__ dst,
                         int K, int N, int total) {
  int i = blockIdx.x * blockDim.x + threadIdx.x;
  if (i < total) {
    int l = i / (K * N);
    int rem = i - l * K * N;
    int k = rem / N;
    int n = rem - k * N;
    dst[((size_t)l * N + n) * K + k] = f2b(src[i]);
  }
}

// ---------------- MFMA helpers ----------------
// wave wv owns output rows wv*16..+15; 8 N-tiles of 16 cols.
// A fragment: row = wv*16 + (lane&15), k = kbase + ks*32 + quad*8 (8 contiguous bf16)
// B (LDS, [N][K] pitch 72): row n = nt*16 + (lane&15), same k window.
// C/D: D[wv*16 + quad*4 + r][nt*16 + (lane&15)] = acc[nt][r]
#define MFMA_STEP(AP, APITCH, AKOFF, ACCN)                                         \
  { _Pragma("unroll")                                                              \
    for (int ks = 0; ks < 2; ++ks) {                                               \
      short8v af_ = *(const short8v*)&AP[(wv * 16 + ln15) * APITCH + (AKOFF) + ks * 32 + quad * 8]; \
      _Pragma("unroll")                                                            \
      for (int nt = 0; nt < 8; ++nt) {                                             \
        short8v bf_ = *(const short8v*)&sB[(nt * 16 + ln15) * 72 + ks * 32 + quad * 8]; \
        ACCN[nt] = __builtin_amdgcn_mfma_f32_16x16x32_bf16(af_, bf_, ACCN[nt], 0, 0, 0); \
      } } }

// stage one 128xKC(=64) B chunk from a pre-transposed [N][K] bf16 weight matrix
#define STAGE_B(EXPR)                                                              \
  { _Pragma("unroll")                                                              \
    for (int i_ = 0; i_ < 4; ++i_) {                                               \
      int flat_ = tid + i_ * 256;                                                  \
      int n = flat_ >> 3, seg = flat_ & 7;                                         \
      *(float4*)&sB[n * 72 + seg * 8] = *(const float4*)&(EXPR);                   \
    } }

// ---------------- per-layer node-side precompute: XAB = x @ [W1a|W1b] ----------------
// out: xab [N_NODES][256] bf16, cols 0..127 = x@W1a (dst part), 128..255 = x@W1b (src part)

__launch_bounds__(256, 4)
__global__ void k_xab(const unsigned short* __restrict__ xb,
                      const unsigned short* __restrict__ mW1t,  // [128n][384k]
                      unsigned short* __restrict__ xab)
{
  __shared__ unsigned short sB[128 * 72];
  const int tid = threadIdx.x;
  const int n0 = blockIdx.x * 64;
  const int wv = tid >> 6, lane = tid & 63, quad = lane >> 4, ln15 = lane & 15;
  const int arow = min(n0 + wv * 16 + ln15, N_NODES - 1);

  // A fragments (K=128 of this node row), reused across both output halves
  short8v afr[2][2];
#pragma unroll
  for (int c = 0; c < 2; ++c)
#pragma unroll
    for (int ks = 0; ks < 2; ++ks)
      afr[c][ks] = *(const short8v*)&xb[(size_t)arow * H + c * 64 + ks * 32 + quad * 8];

  for (int h = 0; h < 2; ++h) {
    f32x4 acc[8];
#pragma unroll
    for (int nt = 0; nt < 8; ++nt) acc[nt] = (f32x4){0.f, 0.f, 0.f, 0.f};
    for (int c = 0; c < 2; ++c) {
      STAGE_B(mW1t[(size_t)n * 384 + h * 128 + c * 64 + seg * 8])
      __syncthreads();
#pragma unroll
      for (int ks = 0; ks < 2; ++ks) {
#pragma unroll
        for (int nt = 0; nt < 8; ++nt) {
          short8v bf = *(const short8v*)&sB[(nt * 16 + ln15) * 72 + ks * 32 + quad * 8];
          acc[nt] = __builtin_amdgcn_mfma_f32_16x16x32_bf16(afr[c][ks], bf, acc[nt], 0, 0, 0);
        }
      }
      __syncthreads();
    }
#pragma unroll
    for (int nt = 0; nt < 8; ++nt) {
      int col = nt * 16 + ln15;
#pragma unroll
      for (int r = 0; r < 4; ++r) {
        int row = n0 + wv * 16 + quad * 4 + r;
        if (row < N_NODES)
          xab[(size_t)row * 256 + h * 128 + col] = f2b(acc[nt][r]);
      }
    }
  }
}

// ---------------- fused edge kernel (bf16 MFMA) ----------------

__launch_bounds__(256, 4)
__global__ void k_edge(const unsigned short* __restrict__ xab,   // [N][256] bf16
                       const float* __restrict__ pos,
                       const float* __restrict__ eattr,
                       const int* __restrict__ srcI,
                       const int* __restrict__ dstI,
                       const int* __restrict__ sorted,
                       const unsigned short* __restrict__ mW1t, const float* __restrict__ mb1,
                       const unsigned short* __restrict__ mW2t, const float* __restrict__ mb2,
                       const unsigned short* __restrict__ aW1t, const float* __restrict__ ab1,
                       const float* __restrict__ aW2, const float* __restrict__ ab2,
                       float* __restrict__ intra,
                       float* __restrict__ pdelta,
                       int do_intra)
{
  __shared__ unsigned short sB[128 * 72];   // B chunk [128][64] bf16, pitch 72
  __shared__ unsigned short sM[64 * 136];   // XA+XB, then h1, then m; [64][128] bf16, pitch 136
  __shared__ int sEid[64], sSrc[64], sDst[64];
  __shared__ float sW[64];
  __shared__ float sPE[64 * 3];

  const int tid = threadIdx.x;
  const int e0 = blockIdx.x * 64;
  const int nv = min(N_EDGES - e0, 64);
  if (tid < 64) {
    int idx = min(e0 + tid, N_EDGES - 1);
    int eid = sorted[idx];
    sEid[tid] = eid; sSrc[tid] = srcI[eid]; sDst[tid] = dstI[eid];
  }
  __syncthreads();

  const int wv = tid >> 6, lane = tid & 63, quad = lane >> 4, ln15 = lane & 15;

  // ---- assemble XA[dst] + XB[src] (pre-bias) into sM ----
#pragma unroll
  for (int i_ = 0; i_ < 4; ++i_) {
    int flat = tid + i_ * 256;          // 0..1023 = 64 rows x 16 seg8
    int row = flat >> 4, sg = flat & 15;
    ushort8v a = *(const ushort8v*)&xab[(size_t)sDst[row] * 256 + sg * 8];
    ushort8v b = *(const ushort8v*)&xab[(size_t)sSrc[row] * 256 + 128 + sg * 8];
    ushort8v o;
#pragma unroll
    for (int j = 0; j < 8; ++j) o[j] = f2b(b2f(a[j]) + b2f(b[j]));
    *(ushort8v*)&sM[row * 136 + sg * 8] = o;
  }

  f32x4 acc[8];
#pragma unroll
  for (int nt = 0; nt < 8; ++nt) acc[nt] = (f32x4){0.f, 0.f, 0.f, 0.f};

  // ---- eattr @ W1c into acc; A fragments direct from global (fp32 -> bf16 in-reg) ----
  const float* aep = eattr + (size_t)sEid[wv * 16 + ln15] * H;
  for (int c = 0; c < 2; ++c) {
    float4 q0 = *(const float4*)(aep + c * 64 + quad * 8);
    float4 q1 = *(const float4*)(aep + c * 64 + quad * 8 + 4);
    float4 q2 = *(const float4*)(aep + c * 64 + 32 + quad * 8);
    float4 q3 = *(const float4*)(aep + c * 64 + 32 + quad * 8 + 4);
    STAGE_B(mW1t[(size_t)n * 384 + 256 + c * 64 + seg * 8])
    __syncthreads();
    short8v af0, af1;
    af0[0] = (short)f2b(q0.x); af0[1] = (short)f2b(q0.y);
    af0[2] = (short)f2b(q0.z); af0[3] = (short)f2b(q0.w);
    af0[4] = (short)f2b(q1.x); af0[5] = (short)f2b(q1.y);
    af0[6] = (short)f2b(q1.z); af0[7] = (short)f2b(q1.w);
    af1[0] = (short)f2b(q2.x); af1[1] = (short)f2b(q2.y);
    af1[2] = (short)f2b(q2.z); af1[3] = (short)f2b(q2.w);
    af1[4] = (short)f2b(q3.x); af1[5] = (short)f2b(q3.y);
    af1[6] = (short)f2b(q3.z); af1[7] = (short)f2b(q3.w);
#pragma unroll
    for (int nt = 0; nt < 8; ++nt) {
      short8v bf = *(const short8v*)&sB[(nt * 16 + ln15) * 72 + quad * 8];
      acc[nt] = __builtin_amdgcn_mfma_f32_16x16x32_bf16(af0, bf, acc[nt], 0, 0, 0);
    }
#pragma unroll
    for (int nt = 0; nt < 8; ++nt) {
      short8v bf = *(const short8v*)&sB[(nt * 16 + ln15) * 72 + 32 + quad * 8];
      acc[nt] = __builtin_amdgcn_mfma_f32_16x16x32_bf16(af1, bf, acc[nt], 0, 0, 0);
    }
    __syncthreads();
  }

  // h1 = relu(acc + XA+XB + mb1) -> sM
#pragma unroll
  for (int nt = 0; nt < 8; ++nt) {
    int col = nt * 16 + ln15;
    float bb = mb1[col];
#pragma unroll
    for (int r = 0; r < 4; ++r) {
      int row = wv * 16 + quad * 4 + r;
      float xv = b2f(sM[row * 136 + col]);
      sM[row * 136 + col] = f2b(fmaxf(acc[nt][r] + xv + bb, 0.f));
      acc[nt][r] = 0.f;
    }
  }
  __syncthreads();

  // ---- GEMM2: h1 [64][128] @ mW2 -> m [64][128]
  for (int c = 0; c < 2; ++c) {
    STAGE_B(mW2t[(size_t)n * 128 + c * 64 + seg * 8])
    __syncthreads();
    MFMA_STEP(sM, 136, c * 64, acc)
    __syncthreads();
  }

  // m = acc + mb2 -> sM (all GEMM2 reads done)
#pragma unroll
  for (int nt = 0; nt < 8; ++nt) {
    int col = nt * 16 + ln15;
    float bb = mb2[col];
#pragma unroll
    for (int r = 0; r < 4; ++r) {
      int row = wv * 16 + quad * 4 + r;
      sM[row * 136 + col] = f2b(acc[nt][r] + bb);
    }
  }
  __syncthreads();

  // ---- acc MLP: w = relu(m @ aW1 + ab1) @ aW2 + ab2
  float wp0 = 0.f, wp1 = 0.f, wp2 = 0.f, wp3 = 0.f;
  for (int h = 0; h < 2; ++h) {
#pragma unroll
    for (int nt = 0; nt < 8; ++nt) acc[nt] = (f32x4){0.f, 0.f, 0.f, 0.f};
    for (int c = 0; c < 2; ++c) {
      STAGE_B(aW1t[((size_t)h * 128 + n) * 128 + c * 64 + seg * 8])
      __syncthreads();
      MFMA_STEP(sM, 136, c * 64, acc)
      __syncthreads();
    }
#pragma unroll
    for (int nt = 0; nt < 8; ++nt) {
      int col = h * 128 + nt * 16 + ln15;
      float bb = ab1[col], a2 = aW2[col];
      wp0 += fmaxf(acc[nt][0] + bb, 0.f) * a2;
      wp1 += fmaxf(acc[nt][1] + bb, 0.f) * a2;
      wp2 += fmaxf(acc[nt][2] + bb, 0.f) * a2;
      wp3 += fmaxf(acc[nt][3] + bb, 0.f) * a2;
    }
  }
  // reduce across the 16 lanes of each quad (cols)
#pragma unroll
  for (int m = 1; m <= 8; m <<= 1) {
    wp0 += __shfl_xor(wp0, m, 64);
    wp1 += __shfl_xor(wp1, m, 64);
    wp2 += __shfl_xor(wp2, m, 64);
    wp3 += __shfl_xor(wp3, m, 64);
  }
  if (ln15 == 0) {
    float b2 = ab2[0];
    sW[wv * 16 + quad * 4 + 0] = wp0 + b2;
    sW[wv * 16 + quad * 4 + 1] = wp1 + b2;
    sW[wv * 16 + quad * 4 + 2] = wp2 + b2;
    sW[wv * 16 + quad * 4 + 3] = wp3 + b2;
  }
  __syncthreads();

  // ---- per-edge acc_e into LDS ----
  if (tid < nv) {
    int s = sSrc[tid], d = sDst[tid];
    float rx = pos[s * 3 + 0] - pos[d * 3 + 0];
    float ry = pos[s * 3 + 1] - pos[d * 3 + 1];
    float rz = pos[s * 3 + 2] - pos[d * 3 + 2];
    float dist = sqrtf(rx * rx + ry * ry + rz * rz);
    float cf = sW[tid] / dist;
    sPE[tid * 3 + 0] = cf * rx;
    sPE[tid * 3 + 1] = cf * ry;
    sPE[tid * 3 + 2] = cf * rz;
  }
  __syncthreads();

  // ---- segment-reduced scatter: pdelta (dst-sorted tiles) ----
  if (tid < 3) {
    float run = 0.0f;
    int cur = -2;
    for (int e = 0; e < 64; ++e) {
      int d = (e < nv) ? sDst[e] : -1;
      if (d != cur) {
        if (cur >= 0 && run != 0.0f) atomicAdd(&pdelta[cur * 3 + tid], run);
        run = 0.0f;
        cur = d;
      }
      if (d >= 0) run += sPE[e * 3 + tid];
    }
    if (cur >= 0 && run != 0.0f) atomicAdd(&pdelta[cur * 3 + tid], run);
  }

  // ---- segment-reduced scatter: intra (m is bf16 in sM) ----
  if (do_intra) {
    int f = tid & 127;
    int hf = tid >> 7;
    int eBeg = hf * 32, eEnd = eBeg + 32;
    float run = 0.0f;
    int cur = -2;
    for (int e = eBeg; e < eEnd; ++e) {
      int d = (e < nv) ? sDst[e] : -1;
      if (d != cur) {
        if (cur >= 0 && run != 0.0f) atomicAdd(&intra[(size_t)cur * H + f], run);
        run = 0.0f;
        cur = d;
      }
      if (d >= 0) run += b2f(sM[e * 136 + f]);
    }
    if (cur >= 0 && run != 0.0f) atomicAdd(&intra[(size_t)cur * H + f], run);
  }
}

// ---------------- node kernel (bf16 MFMA) ----------------

__launch_bounds__(256, 3)
__global__ void k_node(const unsigned short* __restrict__ xb,
                       const float* __restrict__ intra,
                       const float* __restrict__ invd,
                       const unsigned short* __restrict__ nW1t, const float* __restrict__ nb1,
                       const unsigned short* __restrict__ nW2t, const float* __restrict__ nb2,
                       const float* __restrict__ pos_in,
                       const float* __restrict__ pdelta,
                       unsigned short* __restrict__ xb_out,
                       float* __restrict__ pos_out,
                       int compute_x)
{
  __shared__ unsigned short sA[64 * 72];
  __shared__ unsigned short sB[128 * 72];
  __shared__ unsigned short sH[64 * 136];
  const int tid = threadIdx.x;
  const int n0 = blockIdx.x * 64;

  if (tid < 192) {
    int n = n0 + tid / 3, cc = tid % 3;
    if (n < N_NODES)
      pos_out[n * 3 + cc] = pos_in[n * 3 + cc] + pdelta[n * 3 + cc] * invd[n];
  }
  if (!compute_x) return;

  const int wv = tid >> 6, lane = tid & 63, quad = lane >> 4, ln15 = lane & 15;

  f32x4 xacc[8];
#pragma unroll
  for (int nt = 0; nt < 8; ++nt) xacc[nt] = (f32x4){0.f, 0.f, 0.f, 0.f};

  f32x4 acc[8];
  for (int h = 0; h < 2; ++h) {
#pragma unroll
    for (int nt = 0; nt < 8; ++nt) acc[nt] = (f32x4){0.f, 0.f, 0.f, 0.f};
    // GEMM-A: concat(xb, intra*invd) [64][256] @ nW1[:, h*128..] -> h-half
    for (int c = 0; c < 4; ++c) {
#pragma unroll
      for (int i_ = 0; i_ < 2; ++i_) {
        int flat_ = tid + i_ * 256;
        int row = flat_ >> 3, seg = flat_ & 7;
        int n = min(n0 + row, N_NODES - 1);
        if (c < 2) {
          *(float4*)&sA[row * 72 + seg * 8] =
              *(const float4*)&xb[(size_t)n * H + c * 64 + seg * 8];
        } else {
          const float* ip = intra + (size_t)n * H + (c - 2) * 64 + seg * 8;
          float iv = invd[n];
          float4 p0 = *(const float4*)ip;
          float4 p1 = *(const float4*)(ip + 4);
          ushort8v v;
          v[0] = f2b(p0.x * iv); v[1] = f2b(p0.y * iv);
          v[2] = f2b(p0.z * iv); v[3] = f2b(p0.w * iv);
          v[4] = f2b(p1.x * iv); v[5] = f2b(p1.y * iv);
          v[6] = f2b(p1.z * iv); v[7] = f2b(p1.w * iv);
          *(ushort8v*)&sA[row * 72 + seg * 8] = v;
        }
      }
      STAGE_B(nW1t[((size_t)h * 128 + n) * 256 + c * 64 + seg * 8])
      __syncthreads();
      MFMA_STEP(sA, 72, 0, acc)
      __syncthreads();
    }
    // h-half = relu(acc + nb1) -> sH
#pragma unroll
    for (int nt = 0; nt < 8; ++nt) {
      int col = nt * 16 + ln15;
      float bb = nb1[h * 128 + col];
#pragma unroll
      for (int r = 0; r < 4; ++r) {
        int row = wv * 16 + quad * 4 + r;
        sH[row * 136 + col] = f2b(fmaxf(acc[nt][r] + bb, 0.f));
      }
    }
    __syncthreads();
    // GEMM-B partial: sH [64][128] @ nW2[h*128.., :] into xacc
    for (int c2 = 0; c2 < 2; ++c2) {
      STAGE_B(nW2t[(size_t)n * 256 + h * 128 + c2 * 64 + seg * 8])
      __syncthreads();
      MFMA_STEP(sH, 136, c2 * 64, xacc)
      __syncthreads();
    }
  }
  // x_out = xacc + nb2 (bf16)
#pragma unroll
  for (int nt = 0; nt < 8; ++nt) {
    int col = nt * 16 + ln15;
    float bb = nb2[col];
#pragma unroll
    for (int r = 0; r < 4; ++r) {
      int row = n0 + wv * 16 + quad * 4 + r;
      if (row < N_NODES)
        xb_out[(size_t)row * H + col] = f2b(xacc[nt][r] + bb);
    }
  }
}

extern "C" void kernel_launch(void* const* d_in, const int* in_sizes, int n_in,
                              void* d_out, int out_size, void* d_ws, size_t ws_size,
                              hipStream_t stream) {
  const float* x0    = (const float*)d_in[0];
  const int*   eidx  = (const int*)d_in[1];
  const float* eattr = (const float*)d_in[2];
  const float* pos0  = (const float*)d_in[3];
  const float* mW1 = (const float*)d_in[4];
  const float* mb1 = (const float*)d_in[5];
  const float* mW2 = (const float*)d_in[6];
  const float* mb2 = (const float*)d_in[7];
  const float* aW1 = (const float*)d_in[8];
  const float* ab1 = (const float*)d_in[9];
  const float* aW2 = (const float*)d_in[10];
  const float* ab2 = (const float*)d_in[11];
  const float* nW1 = (const float*)d_in[12];
  const float* nb1 = (const float*)d_in[13];
  const float* nW2 = (const float*)d_in[14];
  const float* nb2 = (const float*)d_in[15];
  const int* srcI = eidx;
  const int* dstI = eidx + N_EDGES;

  char* wsb = (char*)d_ws;
  int*   degC    = (int*)wsb;                     wsb += (size_t)N_NODES * 4;
  int*   cursor  = (int*)wsb;                     wsb += (size_t)N_NODES * 4;
  int*   chunkS  = (int*)wsb;                     wsb += 256 * 4;
  int*   sorted  = (int*)wsb;                     wsb += (size_t)N_EDGES * 4;
  float* invd    = (float*)wsb;                   wsb += (size_t)N_NODES * 4;
  float* pdelta  = (float*)wsb;                   wsb += (size_t)3 * N_NODES * 4;
  float* pos_a   = (float*)wsb;                   wsb += (size_t)3 * N_NODES * 4;
  float* pos_b   = (float*)wsb;                   wsb += (size_t)3 * N_NODES * 4;
  float* intra   = (float*)wsb;                   wsb += (size_t)N_NODES * H * 4;
  unsigned short* xb0  = (unsigned short*)wsb;    wsb += (size_t)N_NODES * H * 2;
  unsigned short* xb_a = (unsigned short*)wsb;    wsb += (size_t)N_NODES * H * 2;
  unsigned short* xb_b = (unsigned short*)wsb;    wsb += (size_t)N_NODES * H * 2;
  unsigned short* xabW = (unsigned short*)wsb;    wsb += (size_t)N_NODES * 256 * 2;
  unsigned short* mW1t = (unsigned short*)wsb;    wsb += (size_t)NL * 128 * 384 * 2;
  unsigned short* mW2t = (unsigned short*)wsb;    wsb += (size_t)NL * 128 * 128 * 2;
  unsigned short* aW1t = (unsigned short*)wsb;    wsb += (size_t)NL * 256 * 128 * 2;
  unsigned short* nW1t = (unsigned short*)wsb;    wsb += (size_t)NL * 256 * 256 * 2;
  unsigned short* nW2t = (unsigned short*)wsb;    wsb += (size_t)NL * 128 * 256 * 2;

  // counting sort of edges by dst (every launch; ws is re-poisoned)
  hipMemsetAsync(degC, 0, N_NODES * sizeof(int), stream);
  k_deg_i<<<(N_EDGES + 255) / 256, 256, 0, stream>>>(dstI, degC);
  k_inv<<<(N_NODES + 255) / 256, 256, 0, stream>>>(degC, invd);
  k_scan1<<<NCHUNK, SCAN_B, 0, stream>>>(degC, cursor, chunkS);
  k_scan2<<<1, SCAN_B, 0, stream>>>(chunkS);
  k_scan3<<<NCHUNK, SCAN_B, 0, stream>>>(cursor, chunkS);
  k_scatter_sort<<<(N_EDGES + 255) / 256, 256, 0, stream>>>(dstI, cursor, sorted);

  // bf16 conversions
  {
    int n4 = N_NODES * H / 4;
    k_cvt_x<<<(n4 + 255) / 256, 256, 0, stream>>>(x0, xb0, n4);
    int t1 = NL * 384 * 128;
    k_cvt_wt<<<(t1 + 255) / 256, 256, 0, stream>>>(mW1, mW1t, 384, 128, t1);
    int t2 = NL * 128 * 128;
    k_cvt_wt<<<(t2 + 255) / 256, 256, 0, stream>>>(mW2, mW2t, 128, 128, t2);
    int t3 = NL * 128 * 256;
    k_cvt_wt<<<(t3 + 255) / 256, 256, 0, stream>>>(aW1, aW1t, 128, 256, t3);
    int t4 = NL * 256 * 256;
    k_cvt_wt<<<(t4 + 255) / 256, 256, 0, stream>>>(nW1, nW1t, 256, 256, t4);
    int t5 = NL * 256 * 128;
    k_cvt_wt<<<(t5 + 255) / 256, 256, 0, stream>>>(nW2, nW2t, 256, 128, t5);
  }

  const unsigned short* xc = xb0;
  const float* pc = pos0;
  float* pos_out_final = (float*)d_out;

  for (int l = 0; l < NL; ++l) {
    int last = (l == NL - 1);
    hipMemsetAsync(pdelta, 0, 3 * N_NODES * sizeof(float), stream);
    if (!last)
      hipMemsetAsync(intra, 0, (size_t)N_NODES * H * sizeof(float), stream);

    // node-side precompute of the x-dependent halves of the message MLP input
    k_xab<<<(N_NODES + 63) / 64, 256, 0, stream>>>(
        xc, mW1t + (size_t)l * 128 * 384, xabW);

    k_edge<<<(N_EDGES + 63) / 64, 256, 0, stream>>>(
        xabW, pc, eattr, srcI, dstI, sorted,
        mW1t + (size_t)l * 128 * 384, mb1 + (size_t)l * 128,
        mW2t + (size_t)l * 128 * 128, mb2 + (size_t)l * 128,
        aW1t + (size_t)l * 256 * 128, ab1 + (size_t)l * 256,
        aW2 + (size_t)l * 256, ab2 + l,
        intra, pdelta, last ? 0 : 1);

    float* pn = last ? pos_out_final : (l == 0 ? pos_a : pos_b);
    unsigned short* xn = (l == 0) ? xb_a : xb_b;
    k_node<<<(N_NODES + 63) / 64, 256, 0, stream>>>(
        xc, intra, invd,
        nW1t + (size_t)l * 256 * 256, nb1 + (size_t)l * 256,
        nW2t + (size_t)l * 128 * 256, nb2 + (size_t)l * 128,
        pc, pdelta, xn, pn, last ? 0 : 1);

    xc = xn;
    pc = pn;
  }
}